// Round 16
// baseline (415.618 us; speedup 1.0000x reference)
//
#include <hip/hip_runtime.h>
#include <cstdint>
#include <cstddef>

#define Tsz 200
#define Usz 50
#define Kd  512
#define G4h 2048
#define OD  1000

typedef __attribute__((ext_vector_type(8))) short short8;
typedef __attribute__((ext_vector_type(4))) short s16x4;
typedef __attribute__((ext_vector_type(4))) float f32x4;
typedef __attribute__((ext_vector_type(16))) float f32x16;

__device__ __forceinline__ unsigned short f2bf(float x) {
  union { float f; unsigned u; } v; v.f = x;
  unsigned r = v.u + 0x7FFFu + ((v.u >> 16) & 1u);
  return (unsigned short)(r >> 16);
}
__device__ __forceinline__ float bf2f(unsigned short h) {
  union { unsigned u; float f; } v; v.u = ((unsigned)h) << 16; return v.f;
}
__device__ __forceinline__ void splits(float w, short& hi, short& lo) {
  unsigned short h = f2bf(w);
  hi = (short)h;
  lo = (short)f2bf(w - bf2f(h));
}
__device__ __forceinline__ void split8(float4 f0, float4 f1, short8& hi, short8& lo) {
  float v[8] = {f0.x, f0.y, f0.z, f0.w, f1.x, f1.y, f1.z, f1.w};
  #pragma unroll
  for (int i = 0; i < 8; ++i) { short a, b2; splits(v[i], a, b2); hi[i] = a; lo[i] = b2; }
}
__device__ __forceinline__ float ftanh(float x) {
  float ax = fabsf(x);
  float t = __expf(-2.0f * ax);
  float r = (1.0f - t) / (1.0f + t);
  return copysignf(r, x);
}
__device__ __forceinline__ float sigf(float x) {
  return 1.0f / (1.0f + __expf(-x));
}
__device__ __forceinline__ void astore(unsigned* p, unsigned v) {
  __hip_atomic_store(p, v, __ATOMIC_RELAXED, __HIP_MEMORY_SCOPE_AGENT);
}
__device__ __forceinline__ void gload16(const void* g, void* l) {
  __builtin_amdgcn_global_load_lds(
      (const __attribute__((address_space(1))) void*)g,
      (__attribute__((address_space(3))) void*)l, 16, 0, 0);
}
__device__ __forceinline__ void aload4x4(const unsigned* p0, const unsigned* p1,
                                         const unsigned* p2, const unsigned* p3,
                                         uint4& r0, uint4& r1, uint4& r2, uint4& r3) {
  asm volatile(
      "global_load_dwordx4 %0, %4, off sc0 sc1\n\t"
      "global_load_dwordx4 %1, %5, off sc0 sc1\n\t"
      "global_load_dwordx4 %2, %6, off sc0 sc1\n\t"
      "global_load_dwordx4 %3, %7, off sc0 sc1\n\t"
      "s_waitcnt vmcnt(0)"
      : "=&v"(r0), "=&v"(r1), "=&v"(r2), "=&v"(r3)
      : "v"(p0), "v"(p1), "v"(p2), "v"(p3)
      : "memory");
}
__device__ __forceinline__ void aload8x4(const unsigned* p0, const unsigned* p1,
                                         const unsigned* p2, const unsigned* p3,
                                         const unsigned* q0, const unsigned* q1,
                                         const unsigned* q2, const unsigned* q3,
                                         uint4& r0, uint4& r1, uint4& r2, uint4& r3,
                                         uint4& s0, uint4& s1, uint4& s2, uint4& s3) {
  asm volatile(
      "global_load_dwordx4 %0, %8, off sc0 sc1\n\t"
      "global_load_dwordx4 %1, %9, off sc0 sc1\n\t"
      "global_load_dwordx4 %2, %10, off sc0 sc1\n\t"
      "global_load_dwordx4 %3, %11, off sc0 sc1\n\t"
      "global_load_dwordx4 %4, %12, off sc0 sc1\n\t"
      "global_load_dwordx4 %5, %13, off sc0 sc1\n\t"
      "global_load_dwordx4 %6, %14, off sc0 sc1\n\t"
      "global_load_dwordx4 %7, %15, off sc0 sc1\n\t"
      "s_waitcnt vmcnt(0)"
      : "=&v"(r0), "=&v"(r1), "=&v"(r2), "=&v"(r3),
        "=&v"(s0), "=&v"(s1), "=&v"(s2), "=&v"(s3)
      : "v"(p0), "v"(p1), "v"(p2), "v"(p3),
        "v"(q0), "v"(q1), "v"(q2), "v"(q3)
      : "memory");
}
__device__ __forceinline__ unsigned tagbad4(uint4 v, unsigned tg) {
  return ((v.x ^ tg) | (v.y ^ tg) | (v.z ^ tg) | (v.w ^ tg)) & 0xFFu;
}
__device__ __forceinline__ void bsleep(int slp) {
  for (int s = 0; s < slp; ++s) __builtin_amdgcn_s_sleep(16);
}

// ---------- dispatch 1: init tags + xg GEMM (embed fused) ----------
__global__ __launch_bounds__(256) void k_prep(
    const int* __restrict__ ys, const float* __restrict__ emb,
    const float* __restrict__ Wih0, const float* __restrict__ bih0,
    const float* __restrict__ bhh0,
    unsigned* __restrict__ h0s, unsigned* __restrict__ h1s,
    float* __restrict__ xgr) {
  __shared__ float Al[16 * 516];
  __shared__ int idxs[16];
  const int bid = blockIdx.x;
  const int tid = threadIdx.x;

  if (bid < 16) {
    int i = bid * 256 + tid;
    if (i < 4096) { h0s[i] = 0u; h1s[i] = 0u; }   // f32 0.0 with tag 0
    return;
  }
  int q = bid - 16;
  int m0 = (q % 25) * 16;
  int n0 = (q / 25) * 64;
  if (tid < 16) {
    int m = m0 + tid;
    int u = m >> 3, b = m & 7;
    idxs[tid] = ys[b * Usz + u];
  }
  __syncthreads();
  for (int i = tid; i < 16 * 512; i += 256) {
    int r = i >> 9, k = i & 511;
    int idx = idxs[r];
    Al[r * 516 + k] = (idx == 0) ? 0.0f : emb[(size_t)idx * Kd + k];
  }
  __syncthreads();
  int nl = tid & 63;
  int mg = (tid >> 6) * 4;
  int n = n0 + nl;
  const float* Wr = Wih0 + (size_t)n * Kd;
  float acc[4] = {0.f, 0.f, 0.f, 0.f};
  #pragma unroll 4
  for (int k = 0; k < 512; k += 4) {
    float4 w = *(const float4*)(Wr + k);
    #pragma unroll
    for (int j = 0; j < 4; ++j) {
      const float* ar = &Al[(mg + j) * 516 + k];
      acc[j] += ar[0] * w.x + ar[1] * w.y + ar[2] * w.z + ar[3] * w.w;
    }
  }
  float bias = bih0[n] + bhh0[n];
  int g = n >> 9, jc = n & 511;
  #pragma unroll
  for (int j = 0; j < 4; ++j) {
    int m = m0 + mg + j;
    int u = m >> 3, b = m & 7;
    xgr[(((size_t)u * 32 + (jc >> 4)) * 4 + g) * 128 + (jc & 15) * 8 + b] =
        acc[j] + bias;
  }
}

// ---------- dispatch 2: LSTM (0..95) + Wout-cvt (96..351) + zenc (352..1151)
//            + zdec dataflow (1152..1201, ONE block per u) ----
__global__ __launch_bounds__(256, 1) void k_lstm_zenc(
    const float* __restrict__ Whh0, const float* __restrict__ Wih1,
    const float* __restrict__ Whh1, const float* __restrict__ bih1,
    const float* __restrict__ bhh1, const float* __restrict__ xgr,
    unsigned* __restrict__ h0s, unsigned* __restrict__ h1s,
    const float* __restrict__ Wout, unsigned short* __restrict__ Wb,
    const float* __restrict__ hs, const float* __restrict__ Wenc,
    const float* __restrict__ benc, float* __restrict__ zenc,
    const float* __restrict__ Wdec, float* __restrict__ zdec) {
  __shared__ __align__(16) unsigned short sd[34816];   // 69.6 KB
  unsigned short* H0H = sd;
  unsigned short* H0L = sd + 8192;
  unsigned short* H1H = sd + 16384;
  unsigned short* H1L = sd + 24576;
  float* gsm = (float*)(sd + 32768);

  const int tid = threadIdx.x;
  const int lane = tid & 63;
  const int wv = tid >> 6;
  const int bid = blockIdx.x;

  if (bid >= 1152) {
    // ---- zdec dataflow: one block per u; thread owns n2, n2+1 ----
    float* hl = (float*)sd;                        // 4096 f32 (tagged bits)
    const int u = bid - 1152;
    const int p = u + 1;
    {
      const unsigned* bp = h1s + (size_t)p * 4096 + tid * 16;
      uint4 v0, v1, v2, v3;
      aload4x4(bp, bp + 4, bp + 8, bp + 12, v0, v1, v2, v3);
      const unsigned tg = (unsigned)p & 0xFFu;
      int slp = 1;
      for (int guard = 0; guard < (1 << 14); ++guard) {
        unsigned bad = tagbad4(v0, tg) | tagbad4(v1, tg) |
                       tagbad4(v2, tg) | tagbad4(v3, tg);
        if (!bad) break;
        bsleep(slp);
        if (slp < 8) slp <<= 1;
        aload4x4(bp, bp + 4, bp + 8, bp + 12, v0, v1, v2, v3);
      }
      *(uint4*)&hl[tid * 16] = v0;
      *(uint4*)&hl[tid * 16 + 4] = v1;
      *(uint4*)&hl[tid * 16 + 8] = v2;
      *(uint4*)&hl[tid * 16 + 12] = v3;
    }
    __syncthreads();
    const int n2 = tid * 2;
    const float* w0p = Wdec + (size_t)n2 * Kd;
    const float* w1p = w0p + Kd;
    float acc0[8] = {0, 0, 0, 0, 0, 0, 0, 0};
    float acc1[8] = {0, 0, 0, 0, 0, 0, 0, 0};
    #pragma unroll 4
    for (int kc = 0; kc < 128; ++kc) {
      float4 w0 = *(const float4*)(w0p + kc * 4);
      float4 w1 = *(const float4*)(w1p + kc * 4);
      #pragma unroll
      for (int b = 0; b < 8; ++b) {
        float4 h4 = *(const float4*)&hl[b * 512 + kc * 4];
        acc0[b] += w0.x * h4.x + w0.y * h4.y + w0.z * h4.z + w0.w * h4.w;
        acc1[b] += w1.x * h4.x + w1.y * h4.y + w1.z * h4.z + w1.w * h4.w;
      }
    }
    #pragma unroll
    for (int b = 0; b < 8; ++b) {
      size_t base = ((size_t)(b * Usz + u) << 9);
      zdec[base + n2] = acc0[b];
      zdec[base + n2 + 1] = acc1[b];
    }
    return;
  }
  if (bid >= 352) {
    // ---- zenc GEMM: M=1600, N=512 ----
    float* Al = (float*)sd;
    int q = bid - 352;
    int m0 = (q % 100) * 16;
    int n0 = (q / 100) * 64;
    for (int i = tid; i < 16 * 512; i += 256) {
      int r = i >> 9, k = i & 511;
      Al[r * 516 + k] = hs[(size_t)(m0 + r) * Kd + k];
    }
    __syncthreads();
    int nl = tid & 63;
    int mg = (tid >> 6) * 4;
    int n = n0 + nl;
    const float* Wr = Wenc + (size_t)n * Kd;
    float acc[4] = {0.f, 0.f, 0.f, 0.f};
    #pragma unroll 4
    for (int k = 0; k < 512; k += 4) {
      float4 w = *(const float4*)(Wr + k);
      #pragma unroll
      for (int j = 0; j < 4; ++j) {
        const float* ar = &Al[(mg + j) * 516 + k];
        acc[j] += ar[0] * w.x + ar[1] * w.y + ar[2] * w.z + ar[3] * w.w;
      }
    }
    float bias = benc[n];
    #pragma unroll
    for (int j = 0; j < 4; ++j)
      zenc[(size_t)(m0 + mg + j) * 512 + n] = acc[j] + bias;
    return;
  }
  if (bid >= 96) {
    // ---- Wout fp32 -> bf16, pre-swizzled tile-major (5-bit row XOR,
    //      paired with the 32x32 joint's read swizzle) ----
    int idx = (bid - 96) * 256 + tid;             // 65536 chunks
    int n = idx >> 6, chunk = idx & 63;
    short8 v;
    if (n < OD) {
      const float* src = Wout + (size_t)n * Kd + chunk * 8;
      #pragma unroll
      for (int j = 0; j < 8; ++j) v[j] = (short)f2bf(src[j]);
    } else {
      #pragma unroll
      for (int j = 0; j < 8; ++j) v[j] = 0;
    }
    int tile = n >> 5, srow = n & 31;
    size_t off = (size_t)tile * 32768 + srow * 1024 +
                 ((chunk * 16) ^ (srow << 4));
    *(short8*)((char*)Wb + off) = v;
    return;
  }

  // ---------------- persistent LSTM (blocks 0..95) ----------------
  const int kq = lane >> 4;
  const int cl = lane & 15;
  const int gg = (tid & 127) >> 1;
  const int sub = (tid & 1) << 3;
  const int swz = (gg & 7) << 4;
  const int gbase = gg << 8;
  const int tb = tid >> 7;

  if (bid < 32) {
    // layer 0
    const int j0 = bid * 16;
    short8 whi[16], wlo[16];
    {
      const float* wr = Whh0 + ((size_t)(wv * 512 + j0 + cl)) * Kd;
      #pragma unroll
      for (int kt = 0; kt < 16; ++kt) {
        const float* p4 = wr + kt * 32 + kq * 8;
        split8(*(const float4*)p4, *(const float4*)(p4 + 4), whi[kt], wlo[kt]);
      }
    }
    float creg = 0.0f;
    const int ejl = tid & 15, eb = (tid >> 4) & 7;
    for (int p = 0; p < 50; ++p) {
      const float* xp = xgr + (((size_t)p * 32 + bid) * 4) * 128 + ejl * 8 + eb;
      float x0 = xp[0], x1 = xp[128], x2 = xp[256], x3 = xp[384];
      {
        const unsigned* bp = h0s + (size_t)p * 4096 + (tid << 2);
        uint4 v0, v1, v2, v3;
        aload4x4(bp, bp + 1024, bp + 2048, bp + 3072, v0, v1, v2, v3);
        const unsigned tg = (unsigned)p;
        for (int guard = 0; guard < (1 << 18); ++guard) {
          unsigned bad = tagbad4(v0, tg) | tagbad4(v1, tg) |
                         tagbad4(v2, tg) | tagbad4(v3, tg);
          if (!bad) break;
          __builtin_amdgcn_s_sleep(1);
          aload4x4(bp, bp + 1024, bp + 2048, bp + 3072, v0, v1, v2, v3);
        }
        unsigned uu[4][4] = {{v0.x, v0.y, v0.z, v0.w}, {v1.x, v1.y, v1.z, v1.w},
                             {v2.x, v2.y, v2.z, v2.w}, {v3.x, v3.y, v3.z, v3.w}};
        #pragma unroll
        for (int j = 0; j < 4; ++j) {
          s16x4 hv, lv;
          #pragma unroll
          for (int e = 0; e < 4; ++e) {
            short hh, ll; splits(__uint_as_float(uu[j][e]), hh, ll);
            hv[e] = hh; lv[e] = ll;
          }
          int b = j * 2 + tb;
          int off = gbase + (((b << 4) + sub) ^ swz);
          *(s16x4*)((char*)H0H + off) = hv;
          *(s16x4*)((char*)H0L + off) = lv;
        }
      }
      __syncthreads();
      f32x4 accA = {0.f, 0.f, 0.f, 0.f};
      f32x4 accB = {0.f, 0.f, 0.f, 0.f};
      f32x4 accC = {0.f, 0.f, 0.f, 0.f};
      #pragma unroll
      for (int kt = 0; kt < 16; ++kt) {
        int g = kt * 4 + kq;
        int off = (g << 8) + ((cl << 4) ^ ((g & 7) << 4));
        short8 bh = *(const short8*)((const char*)H0H + off);
        short8 bl = *(const short8*)((const char*)H0L + off);
        accA = __builtin_amdgcn_mfma_f32_16x16x32_bf16(whi[kt], bh, accA, 0, 0, 0);
        accB = __builtin_amdgcn_mfma_f32_16x16x32_bf16(wlo[kt], bh, accB, 0, 0, 0);
        accC = __builtin_amdgcn_mfma_f32_16x16x32_bf16(whi[kt], bl, accC, 0, 0, 0);
      }
      f32x4 acc = (accA + accB) + accC;
      *(f32x4*)&gsm[(wv * 16 + cl) * 16 + kq * 4] = acc;
      __syncthreads();
      if (tid < 128) {
        float g0 = gsm[(0 * 16 + eb) * 16 + ejl];
        float g1 = gsm[(1 * 16 + eb) * 16 + ejl];
        float g2 = gsm[(2 * 16 + eb) * 16 + ejl];
        float g3 = gsm[(3 * 16 + eb) * 16 + ejl];
        float gi = g0 + x0;
        float gf = g1 + x1;
        float gg2 = g2 + x2;
        float go = g3 + x3;
        float cn = sigf(gf) * creg + sigf(gi) * ftanh(gg2);
        float hn = sigf(go) * ftanh(cn);
        creg = cn;
        unsigned hv = (__float_as_uint(hn) & ~0xFFu) | (unsigned)(p + 1);
        astore(h0s + (size_t)(p + 1) * 4096 + eb * 512 + j0 + ejl, hv);
      }
      __syncthreads();
    }
  } else {
    // layer 1
    const int j0 = (bid - 32) * 8;
    const int mt = wv & 1, kh = wv >> 1;
    short8 wihh[8], wihl[8], whhh[8], whhl[8];
    {
      const int g = mt * 2 + (cl >> 3), jl = cl & 7;
      const float* wr0 = Wih1 + ((size_t)(g * 512 + j0 + jl)) * Kd;
      const float* wr1 = Whh1 + ((size_t)(g * 512 + j0 + jl)) * Kd;
      #pragma unroll
      for (int k2 = 0; k2 < 8; ++k2) {
        int kt = kh * 8 + k2;
        const float* p0 = wr0 + kt * 32 + kq * 8;
        const float* p1 = wr1 + kt * 32 + kq * 8;
        split8(*(const float4*)p0, *(const float4*)(p0 + 4), wihh[k2], wihl[k2]);
        split8(*(const float4*)p1, *(const float4*)(p1 + 4), whhh[k2], whhl[k2]);
      }
    }
    float creg = 0.0f;
    const int ejl = tid & 7, eb = (tid >> 3) & 7;
    float bs0 = bih1[0 * 512 + j0 + ejl] + bhh1[0 * 512 + j0 + ejl];
    float bs1 = bih1[1 * 512 + j0 + ejl] + bhh1[1 * 512 + j0 + ejl];
    float bs2 = bih1[2 * 512 + j0 + ejl] + bhh1[2 * 512 + j0 + ejl];
    float bs3 = bih1[3 * 512 + j0 + ejl] + bhh1[3 * 512 + j0 + ejl];
    for (int p = 1; p <= 50; ++p) {
      {
        const unsigned* bp0 = h0s + (size_t)p * 4096 + (tid << 2);
        const unsigned* bp1 = h1s + (size_t)(p - 1) * 4096 + (tid << 2);
        uint4 v0, v1, v2, v3, w0, w1, w2, w3;
        aload8x4(bp0, bp0 + 1024, bp0 + 2048, bp0 + 3072,
                 bp1, bp1 + 1024, bp1 + 2048, bp1 + 3072,
                 v0, v1, v2, v3, w0, w1, w2, w3);
        const unsigned tg0 = (unsigned)p, tg1 = (unsigned)(p - 1);
        for (int guard = 0; guard < (1 << 18); ++guard) {
          unsigned bad = tagbad4(v0, tg0) | tagbad4(v1, tg0) |
                         tagbad4(v2, tg0) | tagbad4(v3, tg0) |
                         tagbad4(w0, tg1) | tagbad4(w1, tg1) |
                         tagbad4(w2, tg1) | tagbad4(w3, tg1);
          if (!bad) break;
          __builtin_amdgcn_s_sleep(1);
          aload8x4(bp0, bp0 + 1024, bp0 + 2048, bp0 + 3072,
                   bp1, bp1 + 1024, bp1 + 2048, bp1 + 3072,
                   v0, v1, v2, v3, w0, w1, w2, w3);
        }
        unsigned uu[4][4] = {{v0.x, v0.y, v0.z, v0.w}, {v1.x, v1.y, v1.z, v1.w},
                             {v2.x, v2.y, v2.z, v2.w}, {v3.x, v3.y, v3.z, v3.w}};
        unsigned tt[4][4] = {{w0.x, w0.y, w0.z, w0.w}, {w1.x, w1.y, w1.z, w1.w},
                             {w2.x, w2.y, w2.z, w2.w}, {w3.x, w3.y, w3.z, w3.w}};
        #pragma unroll
        for (int j = 0; j < 4; ++j) {
          s16x4 hv, lv, hw, lw;
          #pragma unroll
          for (int e = 0; e < 4; ++e) {
            short hh, ll;
            splits(__uint_as_float(uu[j][e]), hh, ll); hv[e] = hh; lv[e] = ll;
            splits(__uint_as_float(tt[j][e]), hh, ll); hw[e] = hh; lw[e] = ll;
          }
          int b = j * 2 + tb;
          int off = gbase + (((b << 4) + sub) ^ swz);
          *(s16x4*)((char*)H0H + off) = hv;
          *(s16x4*)((char*)H0L + off) = lv;
          *(s16x4*)((char*)H1H + off) = hw;
          *(s16x4*)((char*)H1L + off) = lw;
        }
      }
      __syncthreads();
      f32x4 q0 = {0.f,0.f,0.f,0.f}, q1 = {0.f,0.f,0.f,0.f}, q2 = {0.f,0.f,0.f,0.f};
      f32x4 q3 = {0.f,0.f,0.f,0.f}, q4 = {0.f,0.f,0.f,0.f}, q5 = {0.f,0.f,0.f,0.f};
      #pragma unroll
      for (int k2 = 0; k2 < 8; ++k2) {
        int kt = kh * 8 + k2;
        int g = kt * 4 + kq;
        int off = (g << 8) + ((cl << 4) ^ ((g & 7) << 4));
        short8 b0h = *(const short8*)((const char*)H0H + off);
        short8 b0l = *(const short8*)((const char*)H0L + off);
        short8 b1h = *(const short8*)((const char*)H1H + off);
        short8 b1l = *(const short8*)((const char*)H1L + off);
        q0 = __builtin_amdgcn_mfma_f32_16x16x32_bf16(wihh[k2], b0h, q0, 0, 0, 0);
        q1 = __builtin_amdgcn_mfma_f32_16x16x32_bf16(wihl[k2], b0h, q1, 0, 0, 0);
        q2 = __builtin_amdgcn_mfma_f32_16x16x32_bf16(wihh[k2], b0l, q2, 0, 0, 0);
        q3 = __builtin_amdgcn_mfma_f32_16x16x32_bf16(whhh[k2], b1h, q3, 0, 0, 0);
        q4 = __builtin_amdgcn_mfma_f32_16x16x32_bf16(whhl[k2], b1h, q4, 0, 0, 0);
        q5 = __builtin_amdgcn_mfma_f32_16x16x32_bf16(whhh[k2], b1l, q5, 0, 0, 0);
      }
      f32x4 acc = ((q0 + q1) + (q2 + q3)) + (q4 + q5);
      *(f32x4*)&gsm[(wv * 16 + cl) * 16 + kq * 4] = acc;
      __syncthreads();
      if (tid < 64) {
        float gv[4];
        #pragma unroll
        for (int g = 0; g < 4; ++g) {
          int mtg = g >> 1, r = (g & 1) * 8 + ejl;
          gv[g] = gsm[(mtg * 16 + eb) * 16 + r] + gsm[((2 + mtg) * 16 + eb) * 16 + r];
        }
        float gi = gv[0] + bs0, gf = gv[1] + bs1, gg2 = gv[2] + bs2, go = gv[3] + bs3;
        float cn = sigf(gf) * creg + sigf(gi) * ftanh(gg2);
        float hn = sigf(go) * ftanh(cn);
        creg = cn;
        int jg = j0 + ejl;
        unsigned hv = (__float_as_uint(hn) & ~0xFFu) | (unsigned)p;
        astore(h1s + (size_t)p * 4096 + eb * 512 + jg, hv);
      }
      __syncthreads();
    }
  }
}

// ---------- dispatch 3: joint, 32x32x16 MFMA, occupancy pinned to 1 wave/EU
// so the allocator can hold a[32]+acc (~200 VGPR) without spilling (r11's
// failure mode was the 144-VGPR clamp at default occupancy targets).
// 625 blocks x 128 rows (4 waves x 32 rows); counted vmcnt(16).
__global__ __launch_bounds__(256)
__attribute__((amdgpu_waves_per_eu(1, 1)))
void k_joint(
    const float* __restrict__ zenc, const float* __restrict__ zdec,
    const unsigned short* __restrict__ Wb, const float* __restrict__ bout,
    float* __restrict__ out) {
  __shared__ __align__(16) unsigned short Blds[2 * 16384];   // 2 x 32 KB
  __shared__ float blds[1024];
  const int lane = threadIdx.x & 63;
  const int wv = threadIdx.x >> 6;
  const int r32 = lane & 31;
  const int kh = lane >> 5;
  const int rbase = blockIdx.x * 128 + wv * 32;

  for (int i = threadIdx.x; i < 1024; i += 256)
    blds[i] = (i < OD) ? bout[i] : 0.0f;

  // A-fragments: wave owns 32 rows; 32x32x16 A: row = lane&31, k = kh*8 + j
  short8 a[32];
  {
    int row = rbase + r32;
    int u = row % Usz;
    int bt = row / Usz;
    const float* ze = zenc + (size_t)bt * Kd;
    const float* zd = zdec + (size_t)((bt / Tsz) * Usz + u) * Kd;
    #pragma unroll
    for (int kt = 0; kt < 32; ++kt) {
      int k0 = kt * 16 + kh * 8;
      float4 e0 = *(const float4*)(ze + k0);
      float4 e1 = *(const float4*)(ze + k0 + 4);
      float4 d0 = *(const float4*)(zd + k0);
      float4 d1 = *(const float4*)(zd + k0 + 4);
      short8 tt;
      tt[0] = (short)f2bf(ftanh(e0.x + d0.x));
      tt[1] = (short)f2bf(ftanh(e0.y + d0.y));
      tt[2] = (short)f2bf(ftanh(e0.z + d0.z));
      tt[3] = (short)f2bf(ftanh(e0.w + d0.w));
      tt[4] = (short)f2bf(ftanh(e1.x + d1.x));
      tt[5] = (short)f2bf(ftanh(e1.y + d1.y));
      tt[6] = (short)f2bf(ftanh(e1.z + d1.z));
      tt[7] = (short)f2bf(ftanh(e1.w + d1.w));
      a[kt] = tt;
    }
  }

  // prologue: stage W-tile 0 into buffer 0 (linear DMA), full drain once
  #pragma unroll
  for (int i = 0; i < 8; ++i) {
    int o = (i * 4 + wv) * 1024;
    gload16((const char*)Wb + o + lane * 16, (char*)Blds + o);
  }
  asm volatile("s_waitcnt vmcnt(0)" ::: "memory");
  __builtin_amdgcn_s_barrier();
  __builtin_amdgcn_sched_barrier(0);

  int cur = 0;
  for (int it = 0; it < 32; ++it) {
    if (it < 31) {
      const char* g = (const char*)Wb + (size_t)(it + 1) * 32768;
      char* l = (char*)Blds + (cur ^ 1) * 32768;
      #pragma unroll
      for (int i = 0; i < 8; ++i) {
        int o = (i * 4 + wv) * 1024;
        gload16(g + o + lane * 16, l + o);
      }
      __builtin_amdgcn_sched_barrier(0);   // pin DMA issue before compute/stores
    }
    const char* bufc = (const char*)Blds + cur * 32768;
    int n0 = it * 32;
    // B layout: col = lane&31 (LDS row r32), k = kh*8 + j; chunk = 2*kt + kh
    f32x16 accE = {0.f,0.f,0.f,0.f,0.f,0.f,0.f,0.f,0.f,0.f,0.f,0.f,0.f,0.f,0.f,0.f};
    f32x16 accO = {0.f,0.f,0.f,0.f,0.f,0.f,0.f,0.f,0.f,0.f,0.f,0.f,0.f,0.f,0.f,0.f};
    #pragma unroll
    for (int kt = 0; kt < 32; kt += 2) {
      int c0 = kt * 2 + kh;
      int c1 = c0 + 2;
      int o0 = r32 * 1024 + ((c0 * 16) ^ (r32 << 4));
      int o1 = r32 * 1024 + ((c1 * 16) ^ (r32 << 4));
      short8 b0 = *(const short8*)(bufc + o0);
      short8 b1 = *(const short8*)(bufc + o1);
      accE = __builtin_amdgcn_mfma_f32_32x32x16_bf16(a[kt], b0, accE, 0, 0, 0);
      accO = __builtin_amdgcn_mfma_f32_32x32x16_bf16(a[kt + 1], b1, accO, 0, 0, 0);
    }
    f32x16 acc = accE + accO;
    int n = n0 + r32;
    float bo = blds[n];
    if (n < OD) {
      // C/D: col = lane&31, row = (reg&3) + 8*(reg>>2) + 4*kh  [m74/m101]
      size_t base = (size_t)(rbase + kh * 4) * OD + n;
      #pragma unroll
      for (int reg = 0; reg < 16; ++reg) {
        int r = (reg & 3) + 8 * (reg >> 2);
        out[base + (size_t)r * OD] = acc[reg] + bo;
      }
    }
    if (it < 31) {
      __builtin_amdgcn_sched_barrier(0);
      // 16 stores issued after the 8 DMAs => vmcnt(16) forces DMAs retired
      asm volatile("s_waitcnt vmcnt(16)" ::: "memory");
      __builtin_amdgcn_s_barrier();
      __builtin_amdgcn_sched_barrier(0);
    }
    cur ^= 1;
  }
}

extern "C" void kernel_launch(void* const* d_in, const int* in_sizes, int n_in,
                              void* d_out, int out_size, void* d_ws, size_t ws_size,
                              hipStream_t stream) {
  const float* hs   = (const float*)d_in[0];
  const int*   ys   = (const int*)d_in[1];
  const float* emb  = (const float*)d_in[2];
  const float* Wih0 = (const float*)d_in[3];
  const float* Whh0 = (const float*)d_in[4];
  const float* bih0 = (const float*)d_in[5];
  const float* bhh0 = (const float*)d_in[6];
  const float* Wih1 = (const float*)d_in[7];
  const float* Whh1 = (const float*)d_in[8];
  const float* bih1 = (const float*)d_in[9];
  const float* bhh1 = (const float*)d_in[10];
  const float* Wenc = (const float*)d_in[11];
  const float* benc = (const float*)d_in[12];
  const float* Wdec = (const float*)d_in[13];
  const float* Wout = (const float*)d_in[14];
  const float* bout = (const float*)d_in[15];
  float* out = (float*)d_out;

  // layout (floats), no overlaps
  float* ws   = (float*)d_ws;
  float* xgr  = ws + 204800;              // [204800, 1024000)
  float* zenc = ws + 1024000;             // [1024000,1843200)
  float* zdec = ws + 1843200;             // [1843200,2048000)
  unsigned short* Wb = (unsigned short*)(ws + 2252800);  // [2252800,2514944)
  unsigned* h0s = (unsigned*)(ws + 2514944);  // [2514944,2723840)
  unsigned* h1s = (unsigned*)(ws + 2723840);  // [2723840,2932736)

  k_prep<<<816, 256, 0, stream>>>(ys, emb, Wih0, bih0, bhh0, h0s, h1s, xgr);
  k_lstm_zenc<<<1202, 256, 0, stream>>>(Whh0, Wih1, Whh1, bih1, bhh1, xgr,
                                        h0s, h1s, Wout, Wb,
                                        hs, Wenc, benc, zenc, Wdec, zdec);
  k_joint<<<625, 256, 0, stream>>>(zenc, zdec, Wb, bout, out);
}

// Round 17
// 353.596 us; speedup vs baseline: 1.1754x; 1.1754x over previous
//
#include <hip/hip_runtime.h>
#include <cstdint>
#include <cstddef>

#define Tsz 200
#define Usz 50
#define Kd  512
#define G4h 2048
#define OD  1000

typedef __attribute__((ext_vector_type(8))) short short8;
typedef __attribute__((ext_vector_type(4))) short s16x4;
typedef __attribute__((ext_vector_type(4))) float f32x4;

__device__ __forceinline__ unsigned short f2bf(float x) {
  union { float f; unsigned u; } v; v.f = x;
  unsigned r = v.u + 0x7FFFu + ((v.u >> 16) & 1u);
  return (unsigned short)(r >> 16);
}
__device__ __forceinline__ float bf2f(unsigned short h) {
  union { unsigned u; float f; } v; v.u = ((unsigned)h) << 16; return v.f;
}
__device__ __forceinline__ void splits(float w, short& hi, short& lo) {
  unsigned short h = f2bf(w);
  hi = (short)h;
  lo = (short)f2bf(w - bf2f(h));
}
__device__ __forceinline__ void split8(float4 f0, float4 f1, short8& hi, short8& lo) {
  float v[8] = {f0.x, f0.y, f0.z, f0.w, f1.x, f1.y, f1.z, f1.w};
  #pragma unroll
  for (int i = 0; i < 8; ++i) { short a, b2; splits(v[i], a, b2); hi[i] = a; lo[i] = b2; }
}
__device__ __forceinline__ float ftanh(float x) {
  float ax = fabsf(x);
  float t = __expf(-2.0f * ax);
  float r = (1.0f - t) / (1.0f + t);
  return copysignf(r, x);
}
__device__ __forceinline__ float sigf(float x) {
  return 1.0f / (1.0f + __expf(-x));
}
__device__ __forceinline__ void astore(unsigned* p, unsigned v) {
  __hip_atomic_store(p, v, __ATOMIC_RELAXED, __HIP_MEMORY_SCOPE_AGENT);
}
__device__ __forceinline__ void gload16(const void* g, void* l) {
  __builtin_amdgcn_global_load_lds(
      (const __attribute__((address_space(1))) void*)g,
      (__attribute__((address_space(3))) void*)l, 16, 0, 0);
}
__device__ __forceinline__ void aload4x4(const unsigned* p0, const unsigned* p1,
                                         const unsigned* p2, const unsigned* p3,
                                         uint4& r0, uint4& r1, uint4& r2, uint4& r3) {
  asm volatile(
      "global_load_dwordx4 %0, %4, off sc0 sc1\n\t"
      "global_load_dwordx4 %1, %5, off sc0 sc1\n\t"
      "global_load_dwordx4 %2, %6, off sc0 sc1\n\t"
      "global_load_dwordx4 %3, %7, off sc0 sc1\n\t"
      "s_waitcnt vmcnt(0)"
      : "=&v"(r0), "=&v"(r1), "=&v"(r2), "=&v"(r3)
      : "v"(p0), "v"(p1), "v"(p2), "v"(p3)
      : "memory");
}
__device__ __forceinline__ void aload8x4(const unsigned* p0, const unsigned* p1,
                                         const unsigned* p2, const unsigned* p3,
                                         const unsigned* q0, const unsigned* q1,
                                         const unsigned* q2, const unsigned* q3,
                                         uint4& r0, uint4& r1, uint4& r2, uint4& r3,
                                         uint4& s0, uint4& s1, uint4& s2, uint4& s3) {
  asm volatile(
      "global_load_dwordx4 %0, %8, off sc0 sc1\n\t"
      "global_load_dwordx4 %1, %9, off sc0 sc1\n\t"
      "global_load_dwordx4 %2, %10, off sc0 sc1\n\t"
      "global_load_dwordx4 %3, %11, off sc0 sc1\n\t"
      "global_load_dwordx4 %4, %12, off sc0 sc1\n\t"
      "global_load_dwordx4 %5, %13, off sc0 sc1\n\t"
      "global_load_dwordx4 %6, %14, off sc0 sc1\n\t"
      "global_load_dwordx4 %7, %15, off sc0 sc1\n\t"
      "s_waitcnt vmcnt(0)"
      : "=&v"(r0), "=&v"(r1), "=&v"(r2), "=&v"(r3),
        "=&v"(s0), "=&v"(s1), "=&v"(s2), "=&v"(s3)
      : "v"(p0), "v"(p1), "v"(p2), "v"(p3),
        "v"(q0), "v"(q1), "v"(q2), "v"(q3)
      : "memory");
}
__device__ __forceinline__ unsigned tagbad4(uint4 v, unsigned tg) {
  return ((v.x ^ tg) | (v.y ^ tg) | (v.z ^ tg) | (v.w ^ tg)) & 0xFFu;
}
__device__ __forceinline__ void bsleep(int slp) {
  for (int s = 0; s < slp; ++s) __builtin_amdgcn_s_sleep(16);
}

// ---------- dispatch 1: init tags + xg GEMM (embed fused) ----------
__global__ __launch_bounds__(256) void k_prep(
    const int* __restrict__ ys, const float* __restrict__ emb,
    const float* __restrict__ Wih0, const float* __restrict__ bih0,
    const float* __restrict__ bhh0,
    unsigned* __restrict__ h0s, unsigned* __restrict__ h1s,
    float* __restrict__ xgr) {
  __shared__ float Al[16 * 516];
  __shared__ int idxs[16];
  const int bid = blockIdx.x;
  const int tid = threadIdx.x;

  if (bid < 16) {
    int i = bid * 256 + tid;
    if (i < 4096) { h0s[i] = 0u; h1s[i] = 0u; }   // f32 0.0 with tag 0
    return;
  }
  int q = bid - 16;
  int m0 = (q % 25) * 16;
  int n0 = (q / 25) * 64;
  if (tid < 16) {
    int m = m0 + tid;
    int u = m >> 3, b = m & 7;
    idxs[tid] = ys[b * Usz + u];
  }
  __syncthreads();
  for (int i = tid; i < 16 * 512; i += 256) {
    int r = i >> 9, k = i & 511;
    int idx = idxs[r];
    Al[r * 516 + k] = (idx == 0) ? 0.0f : emb[(size_t)idx * Kd + k];
  }
  __syncthreads();
  int nl = tid & 63;
  int mg = (tid >> 6) * 4;
  int n = n0 + nl;
  const float* Wr = Wih0 + (size_t)n * Kd;
  float acc[4] = {0.f, 0.f, 0.f, 0.f};
  #pragma unroll 4
  for (int k = 0; k < 512; k += 4) {
    float4 w = *(const float4*)(Wr + k);
    #pragma unroll
    for (int j = 0; j < 4; ++j) {
      const float* ar = &Al[(mg + j) * 516 + k];
      acc[j] += ar[0] * w.x + ar[1] * w.y + ar[2] * w.z + ar[3] * w.w;
    }
  }
  float bias = bih0[n] + bhh0[n];
  int g = n >> 9, jc = n & 511;
  #pragma unroll
  for (int j = 0; j < 4; ++j) {
    int m = m0 + mg + j;
    int u = m >> 3, b = m & 7;
    xgr[(((size_t)u * 32 + (jc >> 4)) * 4 + g) * 128 + (jc & 15) * 8 + b] =
        acc[j] + bias;
  }
}

// ---------- dispatch 2: LSTM (0..95) + Wout-cvt (96..351) + zenc (352..1151)
//            + zdec dataflow (1152..1201, ONE block per u) ----
__global__ __launch_bounds__(256, 1) void k_lstm_zenc(
    const float* __restrict__ Whh0, const float* __restrict__ Wih1,
    const float* __restrict__ Whh1, const float* __restrict__ bih1,
    const float* __restrict__ bhh1, const float* __restrict__ xgr,
    unsigned* __restrict__ h0s, unsigned* __restrict__ h1s,
    const float* __restrict__ Wout, unsigned short* __restrict__ Wb,
    const float* __restrict__ hs, const float* __restrict__ Wenc,
    const float* __restrict__ benc, float* __restrict__ zenc,
    const float* __restrict__ Wdec, float* __restrict__ zdec) {
  __shared__ __align__(16) unsigned short sd[34816];   // 69.6 KB
  unsigned short* H0H = sd;
  unsigned short* H0L = sd + 8192;
  unsigned short* H1H = sd + 16384;
  unsigned short* H1L = sd + 24576;
  float* gsm = (float*)(sd + 32768);

  const int tid = threadIdx.x;
  const int lane = tid & 63;
  const int wv = tid >> 6;
  const int bid = blockIdx.x;

  if (bid >= 1152) {
    // ---- zdec dataflow: one block per u; thread owns n2, n2+1 ----
    float* hl = (float*)sd;                        // 4096 f32 (tagged bits)
    const int u = bid - 1152;
    const int p = u + 1;
    {
      const unsigned* bp = h1s + (size_t)p * 4096 + tid * 16;
      uint4 v0, v1, v2, v3;
      aload4x4(bp, bp + 4, bp + 8, bp + 12, v0, v1, v2, v3);
      const unsigned tg = (unsigned)p & 0xFFu;
      int slp = 1;
      for (int guard = 0; guard < (1 << 14); ++guard) {
        unsigned bad = tagbad4(v0, tg) | tagbad4(v1, tg) |
                       tagbad4(v2, tg) | tagbad4(v3, tg);
        if (!bad) break;
        bsleep(slp);
        if (slp < 8) slp <<= 1;
        aload4x4(bp, bp + 4, bp + 8, bp + 12, v0, v1, v2, v3);
      }
      *(uint4*)&hl[tid * 16] = v0;
      *(uint4*)&hl[tid * 16 + 4] = v1;
      *(uint4*)&hl[tid * 16 + 8] = v2;
      *(uint4*)&hl[tid * 16 + 12] = v3;
    }
    __syncthreads();
    const int n2 = tid * 2;
    const float* w0p = Wdec + (size_t)n2 * Kd;
    const float* w1p = w0p + Kd;
    float acc0[8] = {0, 0, 0, 0, 0, 0, 0, 0};
    float acc1[8] = {0, 0, 0, 0, 0, 0, 0, 0};
    #pragma unroll 4
    for (int kc = 0; kc < 128; ++kc) {
      float4 w0 = *(const float4*)(w0p + kc * 4);
      float4 w1 = *(const float4*)(w1p + kc * 4);
      #pragma unroll
      for (int b = 0; b < 8; ++b) {
        float4 h4 = *(const float4*)&hl[b * 512 + kc * 4];
        acc0[b] += w0.x * h4.x + w0.y * h4.y + w0.z * h4.z + w0.w * h4.w;
        acc1[b] += w1.x * h4.x + w1.y * h4.y + w1.z * h4.z + w1.w * h4.w;
      }
    }
    #pragma unroll
    for (int b = 0; b < 8; ++b) {
      size_t base = ((size_t)(b * Usz + u) << 9);
      zdec[base + n2] = acc0[b];
      zdec[base + n2 + 1] = acc1[b];
    }
    return;
  }
  if (bid >= 352) {
    // ---- zenc GEMM: M=1600, N=512 ----
    float* Al = (float*)sd;
    int q = bid - 352;
    int m0 = (q % 100) * 16;
    int n0 = (q / 100) * 64;
    for (int i = tid; i < 16 * 512; i += 256) {
      int r = i >> 9, k = i & 511;
      Al[r * 516 + k] = hs[(size_t)(m0 + r) * Kd + k];
    }
    __syncthreads();
    int nl = tid & 63;
    int mg = (tid >> 6) * 4;
    int n = n0 + nl;
    const float* Wr = Wenc + (size_t)n * Kd;
    float acc[4] = {0.f, 0.f, 0.f, 0.f};
    #pragma unroll 4
    for (int k = 0; k < 512; k += 4) {
      float4 w = *(const float4*)(Wr + k);
      #pragma unroll
      for (int j = 0; j < 4; ++j) {
        const float* ar = &Al[(mg + j) * 516 + k];
        acc[j] += ar[0] * w.x + ar[1] * w.y + ar[2] * w.z + ar[3] * w.w;
      }
    }
    float bias = benc[n];
    #pragma unroll
    for (int j = 0; j < 4; ++j)
      zenc[(size_t)(m0 + mg + j) * 512 + n] = acc[j] + bias;
    return;
  }
  if (bid >= 96) {
    // ---- Wout fp32 -> bf16, pre-swizzled tile-major (3-bit row XOR,
    //      paired with the 16x16 joint's read swizzle) ----
    int idx = (bid - 96) * 256 + tid;             // 65536 chunks
    int n = idx >> 6, chunk = idx & 63;
    short8 v;
    if (n < OD) {
      const float* src = Wout + (size_t)n * Kd + chunk * 8;
      #pragma unroll
      for (int j = 0; j < 8; ++j) v[j] = (short)f2bf(src[j]);
    } else {
      #pragma unroll
      for (int j = 0; j < 8; ++j) v[j] = 0;
    }
    int tile = n >> 5, srow = n & 31;
    size_t off = (size_t)tile * 32768 + srow * 1024 +
                 ((chunk * 16) ^ ((srow & 7) << 4));
    *(short8*)((char*)Wb + off) = v;
    return;
  }

  // ---------------- persistent LSTM (blocks 0..95) ----------------
  const int kq = lane >> 4;
  const int cl = lane & 15;
  const int gg = (tid & 127) >> 1;
  const int sub = (tid & 1) << 3;
  const int swz = (gg & 7) << 4;
  const int gbase = gg << 8;
  const int tb = tid >> 7;

  if (bid < 32) {
    // layer 0
    const int j0 = bid * 16;
    short8 whi[16], wlo[16];
    {
      const float* wr = Whh0 + ((size_t)(wv * 512 + j0 + cl)) * Kd;
      #pragma unroll
      for (int kt = 0; kt < 16; ++kt) {
        const float* p4 = wr + kt * 32 + kq * 8;
        split8(*(const float4*)p4, *(const float4*)(p4 + 4), whi[kt], wlo[kt]);
      }
    }
    float creg = 0.0f;
    const int ejl = tid & 15, eb = (tid >> 4) & 7;
    for (int p = 0; p < 50; ++p) {
      const float* xp = xgr + (((size_t)p * 32 + bid) * 4) * 128 + ejl * 8 + eb;
      float x0 = xp[0], x1 = xp[128], x2 = xp[256], x3 = xp[384];
      {
        const unsigned* bp = h0s + (size_t)p * 4096 + (tid << 2);
        uint4 v0, v1, v2, v3;
        aload4x4(bp, bp + 1024, bp + 2048, bp + 3072, v0, v1, v2, v3);
        const unsigned tg = (unsigned)p;
        for (int guard = 0; guard < (1 << 18); ++guard) {
          unsigned bad = tagbad4(v0, tg) | tagbad4(v1, tg) |
                         tagbad4(v2, tg) | tagbad4(v3, tg);
          if (!bad) break;
          __builtin_amdgcn_s_sleep(1);
          aload4x4(bp, bp + 1024, bp + 2048, bp + 3072, v0, v1, v2, v3);
        }
        unsigned uu[4][4] = {{v0.x, v0.y, v0.z, v0.w}, {v1.x, v1.y, v1.z, v1.w},
                             {v2.x, v2.y, v2.z, v2.w}, {v3.x, v3.y, v3.z, v3.w}};
        #pragma unroll
        for (int j = 0; j < 4; ++j) {
          s16x4 hv, lv;
          #pragma unroll
          for (int e = 0; e < 4; ++e) {
            short hh, ll; splits(__uint_as_float(uu[j][e]), hh, ll);
            hv[e] = hh; lv[e] = ll;
          }
          int b = j * 2 + tb;
          int off = gbase + (((b << 4) + sub) ^ swz);
          *(s16x4*)((char*)H0H + off) = hv;
          *(s16x4*)((char*)H0L + off) = lv;
        }
      }
      __syncthreads();
      f32x4 accA = {0.f, 0.f, 0.f, 0.f};
      f32x4 accB = {0.f, 0.f, 0.f, 0.f};
      f32x4 accC = {0.f, 0.f, 0.f, 0.f};
      #pragma unroll
      for (int kt = 0; kt < 16; ++kt) {
        int g = kt * 4 + kq;
        int off = (g << 8) + ((cl << 4) ^ ((g & 7) << 4));
        short8 bh = *(const short8*)((const char*)H0H + off);
        short8 bl = *(const short8*)((const char*)H0L + off);
        accA = __builtin_amdgcn_mfma_f32_16x16x32_bf16(whi[kt], bh, accA, 0, 0, 0);
        accB = __builtin_amdgcn_mfma_f32_16x16x32_bf16(wlo[kt], bh, accB, 0, 0, 0);
        accC = __builtin_amdgcn_mfma_f32_16x16x32_bf16(whi[kt], bl, accC, 0, 0, 0);
      }
      f32x4 acc = (accA + accB) + accC;
      *(f32x4*)&gsm[(wv * 16 + cl) * 16 + kq * 4] = acc;
      __syncthreads();
      if (tid < 128) {
        float g0 = gsm[(0 * 16 + eb) * 16 + ejl];
        float g1 = gsm[(1 * 16 + eb) * 16 + ejl];
        float g2 = gsm[(2 * 16 + eb) * 16 + ejl];
        float g3 = gsm[(3 * 16 + eb) * 16 + ejl];
        float gi = g0 + x0;
        float gf = g1 + x1;
        float gg2 = g2 + x2;
        float go = g3 + x3;
        float cn = sigf(gf) * creg + sigf(gi) * ftanh(gg2);
        float hn = sigf(go) * ftanh(cn);
        creg = cn;
        unsigned hv = (__float_as_uint(hn) & ~0xFFu) | (unsigned)(p + 1);
        astore(h0s + (size_t)(p + 1) * 4096 + eb * 512 + j0 + ejl, hv);
      }
      __syncthreads();
    }
  } else {
    // layer 1
    const int j0 = (bid - 32) * 8;
    const int mt = wv & 1, kh = wv >> 1;
    short8 wihh[8], wihl[8], whhh[8], whhl[8];
    {
      const int g = mt * 2 + (cl >> 3), jl = cl & 7;
      const float* wr0 = Wih1 + ((size_t)(g * 512 + j0 + jl)) * Kd;
      const float* wr1 = Whh1 + ((size_t)(g * 512 + j0 + jl)) * Kd;
      #pragma unroll
      for (int k2 = 0; k2 < 8; ++k2) {
        int kt = kh * 8 + k2;
        const float* p0 = wr0 + kt * 32 + kq * 8;
        const float* p1 = wr1 + kt * 32 + kq * 8;
        split8(*(const float4*)p0, *(const float4*)(p0 + 4), wihh[k2], wihl[k2]);
        split8(*(const float4*)p1, *(const float4*)(p1 + 4), whhh[k2], whhl[k2]);
      }
    }
    float creg = 0.0f;
    const int ejl = tid & 7, eb = (tid >> 3) & 7;
    float bs0 = bih1[0 * 512 + j0 + ejl] + bhh1[0 * 512 + j0 + ejl];
    float bs1 = bih1[1 * 512 + j0 + ejl] + bhh1[1 * 512 + j0 + ejl];
    float bs2 = bih1[2 * 512 + j0 + ejl] + bhh1[2 * 512 + j0 + ejl];
    float bs3 = bih1[3 * 512 + j0 + ejl] + bhh1[3 * 512 + j0 + ejl];
    for (int p = 1; p <= 50; ++p) {
      {
        const unsigned* bp0 = h0s + (size_t)p * 4096 + (tid << 2);
        const unsigned* bp1 = h1s + (size_t)(p - 1) * 4096 + (tid << 2);
        uint4 v0, v1, v2, v3, w0, w1, w2, w3;
        aload8x4(bp0, bp0 + 1024, bp0 + 2048, bp0 + 3072,
                 bp1, bp1 + 1024, bp1 + 2048, bp1 + 3072,
                 v0, v1, v2, v3, w0, w1, w2, w3);
        const unsigned tg0 = (unsigned)p, tg1 = (unsigned)(p - 1);
        for (int guard = 0; guard < (1 << 18); ++guard) {
          unsigned bad = tagbad4(v0, tg0) | tagbad4(v1, tg0) |
                         tagbad4(v2, tg0) | tagbad4(v3, tg0) |
                         tagbad4(w0, tg1) | tagbad4(w1, tg1) |
                         tagbad4(w2, tg1) | tagbad4(w3, tg1);
          if (!bad) break;
          __builtin_amdgcn_s_sleep(1);
          aload8x4(bp0, bp0 + 1024, bp0 + 2048, bp0 + 3072,
                   bp1, bp1 + 1024, bp1 + 2048, bp1 + 3072,
                   v0, v1, v2, v3, w0, w1, w2, w3);
        }
        unsigned uu[4][4] = {{v0.x, v0.y, v0.z, v0.w}, {v1.x, v1.y, v1.z, v1.w},
                             {v2.x, v2.y, v2.z, v2.w}, {v3.x, v3.y, v3.z, v3.w}};
        unsigned tt[4][4] = {{w0.x, w0.y, w0.z, w0.w}, {w1.x, w1.y, w1.z, w1.w},
                             {w2.x, w2.y, w2.z, w2.w}, {w3.x, w3.y, w3.z, w3.w}};
        #pragma unroll
        for (int j = 0; j < 4; ++j) {
          s16x4 hv, lv, hw, lw;
          #pragma unroll
          for (int e = 0; e < 4; ++e) {
            short hh, ll;
            splits(__uint_as_float(uu[j][e]), hh, ll); hv[e] = hh; lv[e] = ll;
            splits(__uint_as_float(tt[j][e]), hh, ll); hw[e] = hh; lw[e] = ll;
          }
          int b = j * 2 + tb;
          int off = gbase + (((b << 4) + sub) ^ swz);
          *(s16x4*)((char*)H0H + off) = hv;
          *(s16x4*)((char*)H0L + off) = lv;
          *(s16x4*)((char*)H1H + off) = hw;
          *(s16x4*)((char*)H1L + off) = lw;
        }
      }
      __syncthreads();
      f32x4 q0 = {0.f,0.f,0.f,0.f}, q1 = {0.f,0.f,0.f,0.f}, q2 = {0.f,0.f,0.f,0.f};
      f32x4 q3 = {0.f,0.f,0.f,0.f}, q4 = {0.f,0.f,0.f,0.f}, q5 = {0.f,0.f,0.f,0.f};
      #pragma unroll
      for (int k2 = 0; k2 < 8; ++k2) {
        int kt = kh * 8 + k2;
        int g = kt * 4 + kq;
        int off = (g << 8) + ((cl << 4) ^ ((g & 7) << 4));
        short8 b0h = *(const short8*)((const char*)H0H + off);
        short8 b0l = *(const short8*)((const char*)H0L + off);
        short8 b1h = *(const short8*)((const char*)H1H + off);
        short8 b1l = *(const short8*)((const char*)H1L + off);
        q0 = __builtin_amdgcn_mfma_f32_16x16x32_bf16(wihh[k2], b0h, q0, 0, 0, 0);
        q1 = __builtin_amdgcn_mfma_f32_16x16x32_bf16(wihl[k2], b0h, q1, 0, 0, 0);
        q2 = __builtin_amdgcn_mfma_f32_16x16x32_bf16(wihh[k2], b0l, q2, 0, 0, 0);
        q3 = __builtin_amdgcn_mfma_f32_16x16x32_bf16(whhh[k2], b1h, q3, 0, 0, 0);
        q4 = __builtin_amdgcn_mfma_f32_16x16x32_bf16(whhl[k2], b1h, q4, 0, 0, 0);
        q5 = __builtin_amdgcn_mfma_f32_16x16x32_bf16(whhh[k2], b1l, q5, 0, 0, 0);
      }
      f32x4 acc = ((q0 + q1) + (q2 + q3)) + (q4 + q5);
      *(f32x4*)&gsm[(wv * 16 + cl) * 16 + kq * 4] = acc;
      __syncthreads();
      if (tid < 64) {
        float gv[4];
        #pragma unroll
        for (int g = 0; g < 4; ++g) {
          int mtg = g >> 1, r = (g & 1) * 8 + ejl;
          gv[g] = gsm[(mtg * 16 + eb) * 16 + r] + gsm[((2 + mtg) * 16 + eb) * 16 + r];
        }
        float gi = gv[0] + bs0, gf = gv[1] + bs1, gg2 = gv[2] + bs2, go = gv[3] + bs3;
        float cn = sigf(gf) * creg + sigf(gi) * ftanh(gg2);
        float hn = sigf(go) * ftanh(cn);
        creg = cn;
        int jg = j0 + ejl;
        unsigned hv = (__float_as_uint(hn) & ~0xFFu) | (unsigned)p;
        astore(h1s + (size_t)p * 4096 + eb * 512 + jg, hv);
      }
      __syncthreads();
    }
  }
}

// ---------- dispatch 3: joint (r12 verbatim: 16x16, a[16], vmcnt(8)) ----------
__global__ __launch_bounds__(256) void k_joint(const float* __restrict__ zenc,
                                               const float* __restrict__ zdec,
                                               const unsigned short* __restrict__ Wb,
                                               const float* __restrict__ bout,
                                               float* __restrict__ out) {
  __shared__ __align__(16) unsigned short Blds[2 * 16384];    // 2 x 32 KB
  const int lane = threadIdx.x & 63;
  const int wv = threadIdx.x >> 6;
  const int kgrp = lane >> 4;
  const int rl = lane & 15;
  const int rbase = blockIdx.x * 64 + wv * 16;

  short8 a[16];
  {
    int row = rbase + rl;
    int u = row % Usz;
    int bt = row / Usz;
    const float* ze = zenc + (size_t)bt * Kd;
    const float* zd = zdec + (size_t)((bt / Tsz) * Usz + u) * Kd;
    #pragma unroll
    for (int kk = 0; kk < 16; ++kk) {
      int k0 = kk * 32 + kgrp * 8;
      float4 e0 = *(const float4*)(ze + k0);
      float4 e1 = *(const float4*)(ze + k0 + 4);
      float4 d0 = *(const float4*)(zd + k0);
      float4 d1 = *(const float4*)(zd + k0 + 4);
      short8 tt;
      tt[0] = (short)f2bf(ftanh(e0.x + d0.x));
      tt[1] = (short)f2bf(ftanh(e0.y + d0.y));
      tt[2] = (short)f2bf(ftanh(e0.z + d0.z));
      tt[3] = (short)f2bf(ftanh(e0.w + d0.w));
      tt[4] = (short)f2bf(ftanh(e1.x + d1.x));
      tt[5] = (short)f2bf(ftanh(e1.y + d1.y));
      tt[6] = (short)f2bf(ftanh(e1.z + d1.z));
      tt[7] = (short)f2bf(ftanh(e1.w + d1.w));
      a[kk] = tt;
    }
  }

  #pragma unroll
  for (int i = 0; i < 8; ++i) {
    int o = (i * 4 + wv) * 1024;
    gload16((const char*)Wb + o + lane * 16, (char*)Blds + o);
  }
  asm volatile("s_waitcnt vmcnt(0)" ::: "memory");
  __builtin_amdgcn_s_barrier();
  __builtin_amdgcn_sched_barrier(0);

  int cur = 0;
  for (int it = 0; it < 32; ++it) {
    if (it < 31) {
      const char* g = (const char*)Wb + (size_t)(it + 1) * 32768;
      char* l = (char*)Blds + (cur ^ 1) * 32768;
      #pragma unroll
      for (int i = 0; i < 8; ++i) {
        int o = (i * 4 + wv) * 1024;
        gload16(g + o + lane * 16, l + o);
      }
      __builtin_amdgcn_sched_barrier(0);
    }
    const char* bufc = (const char*)Blds + cur * 32768;
    int n0 = it * 32;
    f32x4 acc0 = {0.f, 0.f, 0.f, 0.f};
    f32x4 acc1 = {0.f, 0.f, 0.f, 0.f};
    #pragma unroll
    for (int kk = 0; kk < 16; ++kk) {
      int c = kk * 4 + kgrp;
      int b0 = ((c * 16) ^ ((rl & 7) << 4)) + rl * 1024;
      int b1 = ((c * 16) ^ ((rl & 7) << 4)) + (rl + 16) * 1024;
      short8 bf0 = *(const short8*)(bufc + b0);
      short8 bf1 = *(const short8*)(bufc + b1);
      acc0 = __builtin_amdgcn_mfma_f32_16x16x32_bf16(a[kk], bf0, acc0, 0, 0, 0);
      acc1 = __builtin_amdgcn_mfma_f32_16x16x32_bf16(a[kk], bf1, acc1, 0, 0, 0);
    }
    #pragma unroll
    for (int nt = 0; nt < 2; ++nt) {
      int n = n0 + nt * 16 + rl;
      if (n < OD) {
        float bo = bout[n];
        const f32x4& A0 = nt ? acc1 : acc0;
        size_t r0 = (size_t)(rbase + kgrp * 4) * OD + n;
        #pragma unroll
        for (int j = 0; j < 4; ++j)
          out[r0 + (size_t)j * OD] = A0[j] + bo;
      }
    }
    if (it < 31) {
      __builtin_amdgcn_sched_barrier(0);
      asm volatile("s_waitcnt vmcnt(8)" ::: "memory");
      __builtin_amdgcn_s_barrier();
      __builtin_amdgcn_sched_barrier(0);
    }
    cur ^= 1;
  }
}

extern "C" void kernel_launch(void* const* d_in, const int* in_sizes, int n_in,
                              void* d_out, int out_size, void* d_ws, size_t ws_size,
                              hipStream_t stream) {
  const float* hs   = (const float*)d_in[0];
  const int*   ys   = (const int*)d_in[1];
  const float* emb  = (const float*)d_in[2];
  const float* Wih0 = (const float*)d_in[3];
  const float* Whh0 = (const float*)d_in[4];
  const float* bih0 = (const float*)d_in[5];
  const float* bhh0 = (const float*)d_in[6];
  const float* Wih1 = (const float*)d_in[7];
  const float* Whh1 = (const float*)d_in[8];
  const float* bih1 = (const float*)d_in[9];
  const float* bhh1 = (const float*)d_in[10];
  const float* Wenc = (const float*)d_in[11];
  const float* benc = (const float*)d_in[12];
  const float* Wdec = (const float*)d_in[13];
  const float* Wout = (const float*)d_in[14];
  const float* bout = (const float*)d_in[15];
  float* out = (float*)d_out;

  // layout (floats), no overlaps
  float* ws   = (float*)d_ws;
  float* xgr  = ws + 204800;              // [204800, 1024000)
  float* zenc = ws + 1024000;             // [1024000,1843200)
  float* zdec = ws + 1843200;             // [1843200,2048000)
  unsigned short* Wb = (unsigned short*)(ws + 2252800);  // [2252800,2514944)
  unsigned* h0s = (unsigned*)(ws + 2514944);  // [2514944,2723840)
  unsigned* h1s = (unsigned*)(ws + 2723840);  // [2723840,2932736)

  k_prep<<<816, 256, 0, stream>>>(ys, emb, Wih0, bih0, bhh0, h0s, h1s, xgr);
  k_lstm_zenc<<<1202, 256, 0, stream>>>(Whh0, Wih1, Whh1, bih1, bhh1, xgr,
                                        h0s, h1s, Wout, Wb,
                                        hs, Wenc, benc, zenc, Wdec, zdec);
  k_joint<<<1250, 256, 0, stream>>>(zenc, zdec, Wb, bout, out);
}